// Round 1
// baseline (637.612 us; speedup 1.0000x reference)
//
#include <hip/hip_runtime.h>
#include <math.h>

#define D 128
#define NN 256
#define NB 2048          // B*N rows of h
#define FF 512

typedef float f32x4 __attribute__((ext_vector_type(4)));
typedef __bf16 bf16x8 __attribute__((ext_vector_type(8)));

__device__ __forceinline__ float gelu_f(float x) {
  float x3 = x * x * x;
  float u = 0.7978845608028654f * (x + 0.044715f * x3);
  return 0.5f * x * (1.0f + tanhf(u));
}

// ---------------------------------------------------------------------------
// K0: pack Cw [128k x 128d] into bf16 MFMA B-fragment order.
// frag index (nt,ks): lane l, elem i -> Cw[ks*32 + (l>>4)*8 + i][nt*16 + (l&15)]
// stored at ws0[((nt*4+ks)*64 + l)*8 + i]
// ---------------------------------------------------------------------------
__global__ __launch_bounds__(256) void k0_pack(const float* __restrict__ Cw,
                                               __bf16* __restrict__ ws0) {
  int tid = blockIdx.x * 256 + threadIdx.x;  // 0..2047 = nt*256 + ks*64 + l
  int nt = tid >> 8;
  int ks = (tid >> 6) & 3;
  int l  = tid & 63;
  int d  = nt * 16 + (l & 15);
  int kb = ks * 32 + (l >> 4) * 8;
  bf16x8 v;
#pragma unroll
  for (int q = 0; q < 8; ++q) v[q] = (__bf16)Cw[(kb + q) * D + d];
  *(bf16x8*)(ws0 + tid * 8) = v;
}

// ---------------------------------------------------------------------------
// K1: Uh/Vh/Ah/Bh = h @ {U,V,A,B}w + bias.  One block per h-row.
// ---------------------------------------------------------------------------
__global__ __launch_bounds__(256) void k1_lin4(
    const float* __restrict__ h,
    const float* __restrict__ Uw, const float* __restrict__ Ub,
    const float* __restrict__ Vw, const float* __restrict__ Vb,
    const float* __restrict__ Aw, const float* __restrict__ Ab,
    const float* __restrict__ Bw, const float* __restrict__ Bb,
    float* __restrict__ wsU, float* __restrict__ wsV,
    float* __restrict__ wsA, float* __restrict__ wsB) {
  __shared__ float hrow[D];
  int row = blockIdx.x;
  int t = threadIdx.x;
  if (t < D) hrow[t] = h[row * D + t];
  __syncthreads();
  int d = t & 127;
  bool lo = (t < 128);
  const float* W0 = lo ? Uw : Vw;
  const float* W1m = lo ? Aw : Bw;
  float a0 = (lo ? Ub : Vb)[d];
  float a1 = (lo ? Ab : Bb)[d];
#pragma unroll 4
  for (int k = 0; k < D; ++k) {
    float hk = hrow[k];
    a0 = fmaf(hk, W0[k * D + d], a0);
    a1 = fmaf(hk, W1m[k * D + d], a1);
  }
  (lo ? wsU : wsV)[row * D + d] = a0;
  (lo ? wsA : wsB)[row * D + d] = a1;
}

// ---------------------------------------------------------------------------
// K2/K5: the e-pass.  One block per (b,i); 4 waves; wave w owns j in [w*64,w*64+64).
// e_new[j][d] = (e[b,i,j,:] @ Cw)[d] + Cb[d] + Bh[b,i,d] + Ah[b,j,d]   (bf16 MFMA GEMM)
// PASS_D==0: accumulate per-channel {sum, sumsq} of e_new and h-partial
//            sum_j sigmoid(e_new)*Vh[b,j,d]; write block partials to wsP.
// PASS_D==1: e_out = relu(gamma*(e_new-mean)*rstd + beta) + e_in  -> d_out.
// ---------------------------------------------------------------------------
template <int PASS_D>
__global__ __launch_bounds__(256) void k_epass(
    const float* __restrict__ e,
    const __bf16* __restrict__ ws0,
    const float* __restrict__ Ah,
    const float* __restrict__ Bh,
    const float* __restrict__ Vh,
    const float* __restrict__ Cb,
    const float* __restrict__ gamma_e,
    const float* __restrict__ beta_e,
    const float* __restrict__ stats,  // [0:128) mean_e, [128:256) rstd_e
    float* __restrict__ wsP,
    float* __restrict__ out_e) {
  __shared__ __align__(16) __bf16 bfr[16384];  // 32 KB of B-fragments
  __shared__ float red[4][3][128];
  const int t = threadIdx.x;
  const int blk = blockIdx.x;   // blk = b*256 + i
  const int b = blk >> 8;

  // stage packed Cw fragments into LDS (linear copy, 16B per thread per iter)
#pragma unroll
  for (int c = 0; c < 8; ++c) {
    int idx = c * 256 + t;
    *(f32x4*)(bfr + idx * 8) = *(const f32x4*)(ws0 + idx * 8);
  }
  __syncthreads();

  const int w = t >> 6;
  const int l = t & 63;
  const int l15 = l & 15;
  const int lhi = l >> 4;

  float cbias[8], gr[8], mb[8];
#pragma unroll
  for (int nt = 0; nt < 8; ++nt) {
    int d = nt * 16 + l15;
    cbias[nt] = Cb[d] + Bh[blk * D + d];
    if (PASS_D) {
      float g = gamma_e[d] * stats[128 + d];
      gr[nt] = g;
      mb[nt] = beta_e[d] - stats[d] * g;
    } else {
      gr[nt] = 0.f; mb[nt] = 0.f;
    }
  }
  float es[8], eq[8], hp[8];
#pragma unroll
  for (int nt = 0; nt < 8; ++nt) { es[nt] = 0.f; eq[nt] = 0.f; hp[nt] = 0.f; }

  const float* eblk = e + (size_t)blk * (NN * D);
  const float* AhB = Ah + ((size_t)b << 15);
  const float* VhB = Vh + ((size_t)b << 15);
  float* outB = out_e + (size_t)blk * (NN * D);

#pragma unroll 1
  for (int mt = 0; mt < 4; ++mt) {
    const int J0 = w * 64 + mt * 16;
    // A fragments straight from global (f32 -> bf16 in regs)
    bf16x8 af[4];
    const float* ap = eblk + (J0 + l15) * D + lhi * 8;
#pragma unroll
    for (int ks = 0; ks < 4; ++ks) {
      f32x4 f0 = *(const f32x4*)(ap + ks * 32);
      f32x4 f1 = *(const f32x4*)(ap + ks * 32 + 4);
      bf16x8 a;
      a[0] = (__bf16)f0.x; a[1] = (__bf16)f0.y; a[2] = (__bf16)f0.z; a[3] = (__bf16)f0.w;
      a[4] = (__bf16)f1.x; a[5] = (__bf16)f1.y; a[6] = (__bf16)f1.z; a[7] = (__bf16)f1.w;
      af[ks] = a;
    }
    f32x4 acc[8];
    const f32x4 zero = {0.f, 0.f, 0.f, 0.f};
#pragma unroll
    for (int nt = 0; nt < 8; ++nt) acc[nt] = zero;
#pragma unroll
    for (int ks = 0; ks < 4; ++ks) {
#pragma unroll
      for (int nt = 0; nt < 8; ++nt) {
        bf16x8 bfrg = *(const bf16x8*)(bfr + ((nt * 4 + ks) * 64 + l) * 8);
        acc[nt] = __builtin_amdgcn_mfma_f32_16x16x32_bf16(af[ks], bfrg, acc[nt], 0, 0, 0);
      }
    }
    // epilogue: acc[nt][r] is e_new contribution at (j = J0 + lhi*4 + r, d = nt*16 + l15)
#pragma unroll
    for (int nt = 0; nt < 8; ++nt) {
      const int d = nt * 16 + l15;
#pragma unroll
      for (int r = 0; r < 4; ++r) {
        const int j = J0 + lhi * 4 + r;
        float v = acc[nt][r] + cbias[nt] + AhB[j * D + d];
        if (!PASS_D) {
          es[nt] += v;
          eq[nt] = fmaf(v, v, eq[nt]);
          float g = 1.0f / (1.0f + expf(-v));
          hp[nt] = fmaf(g, VhB[j * D + d], hp[nt]);
        } else {
          float wv = fmaxf(fmaf(v, gr[nt], mb[nt]), 0.0f);
          outB[j * D + d] = wv + eblk[j * D + d];
        }
      }
    }
  }

  if (!PASS_D) {
    // reduce over the 4 lane-groups (j sub-rows) within the wave
#pragma unroll
    for (int nt = 0; nt < 8; ++nt) {
      es[nt] += __shfl_xor(es[nt], 16); es[nt] += __shfl_xor(es[nt], 32);
      eq[nt] += __shfl_xor(eq[nt], 16); eq[nt] += __shfl_xor(eq[nt], 32);
      hp[nt] += __shfl_xor(hp[nt], 16); hp[nt] += __shfl_xor(hp[nt], 32);
    }
    if (l < 16) {
#pragma unroll
      for (int nt = 0; nt < 8; ++nt) {
        red[w][0][nt * 16 + l] = es[nt];
        red[w][1][nt * 16 + l] = eq[nt];
        red[w][2][nt * 16 + l] = hp[nt];
      }
    }
    __syncthreads();
    if (t < 128) {
      float S = red[0][0][t] + red[1][0][t] + red[2][0][t] + red[3][0][t];
      float Q = red[0][1][t] + red[1][1][t] + red[2][1][t] + red[3][1][t];
      float H = red[0][2][t] + red[1][2][t] + red[2][2][t] + red[3][2][t];
      wsP[blk * 384 + t] = S;
      wsP[blk * 384 + 128 + t] = Q;
      wsP[blk * 384 + 256 + t] = H;
    }
  }
}

// ---------------------------------------------------------------------------
// K3a: stage-1 reduce of block partials (64 blocks x 32 slots each) and
//      h_new = Uh + hsum (written to ws7) with h-stat partials.
// ---------------------------------------------------------------------------
__global__ __launch_bounds__(256) void k3a(const float* __restrict__ wsP,
                                           const float* __restrict__ wsU,
                                           float* __restrict__ ws7,
                                           float* __restrict__ wsPB) {
  __shared__ float red2[2][4][128];
  int t = threadIdx.x, blk = blockIdx.x;
  int c = t & 127, half = t >> 7;
  float es = 0.f, eq = 0.f, hs = 0.f, hq = 0.f;
  for (int s = 0; s < 16; ++s) {
    int row = blk * 32 + half * 16 + s;
    es += wsP[row * 384 + c];
    eq += wsP[row * 384 + 128 + c];
    float v = wsU[row * D + c] + wsP[row * 384 + 256 + c];
    ws7[row * D + c] = v;
    hs += v;
    hq = fmaf(v, v, hq);
  }
  red2[half][0][c] = es; red2[half][1][c] = eq;
  red2[half][2][c] = hs; red2[half][3][c] = hq;
  __syncthreads();
  if (t < 128) {
#pragma unroll
    for (int k = 0; k < 4; ++k)
      wsPB[blk * 512 + k * 128 + t] = red2[0][k][t] + red2[1][k][t];
  }
}

// K3b: final stats.  ws6: [0:128) mean_e, [128:256) rstd_e, [256:384) mean_h, [384:512) rstd_h
__global__ __launch_bounds__(256) void k3b(const float* __restrict__ wsPB,
                                           float* __restrict__ ws6) {
  int t = threadIdx.x;
  int c = t & 127, g = t >> 7;  // g=0: e-stats, g=1: h-stats
  float S = 0.f, Q = 0.f;
  for (int blk = 0; blk < 64; ++blk) {
    S += wsPB[blk * 512 + (g * 2) * 128 + c];
    Q += wsPB[blk * 512 + (g * 2 + 1) * 128 + c];
  }
  float M = g ? 2048.0f : 524288.0f;
  float mean = S / M;
  float var = Q / M - mean * mean;
  float rstd = rsqrtf(var + 1e-5f);
  ws6[g * 256 + c] = mean;
  ws6[g * 256 + 128 + c] = rstd;
}

// ---------------------------------------------------------------------------
// K4: h-side: BN_h, MLP (gelu), residual.  One block per row.
// ---------------------------------------------------------------------------
__global__ __launch_bounds__(256) void k4_mlp(
    const float* __restrict__ ws7, const float* __restrict__ ws6,
    const float* __restrict__ gamma_h, const float* __restrict__ beta_h,
    const float* __restrict__ W1, const float* __restrict__ b1,
    const float* __restrict__ W2, const float* __restrict__ b2,
    const float* __restrict__ h_in, float* __restrict__ out_h) {
  __shared__ float hn[D];
  __shared__ float t1[FF];
  int row = blockIdx.x, t = threadIdx.x;
  if (t < D) {
    float v = ws7[row * D + t];
    hn[t] = gamma_h[t] * (v - ws6[256 + t]) * ws6[384 + t] + beta_h[t];
  }
  __syncthreads();
  {
    int f0 = t, f1 = t + 256;
    float a0 = b1[f0], a1 = b1[f1];
#pragma unroll 4
    for (int k = 0; k < D; ++k) {
      float hk = hn[k];
      a0 = fmaf(hk, W1[k * FF + f0], a0);
      a1 = fmaf(hk, W1[k * FF + f1], a1);
    }
    t1[f0] = gelu_f(a0);
    t1[f1] = gelu_f(a1);
  }
  __syncthreads();
  if (t < D) {
    float a = b2[t];
#pragma unroll 4
    for (int k = 0; k < FF; ++k) a = fmaf(t1[k], W2[k * D + t], a);
    out_h[row * D + t] = h_in[row * D + t] + a;
  }
}

// ---------------------------------------------------------------------------
extern "C" void kernel_launch(void* const* d_in, const int* in_sizes, int n_in,
                              void* d_out, int out_size, void* d_ws, size_t ws_size,
                              hipStream_t stream) {
  (void)in_sizes; (void)n_in; (void)out_size; (void)ws_size;
  const float* h       = (const float*)d_in[0];
  const float* e       = (const float*)d_in[1];
  const float* Uw      = (const float*)d_in[2];
  const float* Ub      = (const float*)d_in[3];
  const float* Vw      = (const float*)d_in[4];
  const float* Vb      = (const float*)d_in[5];
  const float* Aw      = (const float*)d_in[6];
  const float* Ab      = (const float*)d_in[7];
  const float* Bw      = (const float*)d_in[8];
  const float* Bb      = (const float*)d_in[9];
  const float* Cw      = (const float*)d_in[10];
  const float* Cb      = (const float*)d_in[11];
  const float* gamma_h = (const float*)d_in[12];
  const float* beta_h  = (const float*)d_in[13];
  const float* gamma_e = (const float*)d_in[14];
  const float* beta_e  = (const float*)d_in[15];
  const float* W1      = (const float*)d_in[16];
  const float* b1      = (const float*)d_in[17];
  const float* W2      = (const float*)d_in[18];
  const float* b2      = (const float*)d_in[19];

  float* ws   = (float*)d_ws;
  __bf16* ws0 = (__bf16*)ws;          // 16384 bf16 (8192 floats)
  float* wsU  = ws + 8192;
  float* wsV  = wsU + NB * D;
  float* wsA  = wsV + NB * D;
  float* wsB  = wsA + NB * D;
  float* wsP  = wsB + NB * D;         // 2048 * 384
  float* wsPB = wsP + NB * 384;       // 64 * 512
  float* ws6  = wsPB + 64 * 512;      // 512 stats
  float* ws7  = ws6 + 512;            // h_new 2048*128

  float* out_h = (float*)d_out;
  float* out_e = out_h + NB * D;

  k0_pack<<<dim3(8), dim3(256), 0, stream>>>(Cw, ws0);
  k1_lin4<<<dim3(NB), dim3(256), 0, stream>>>(h, Uw, Ub, Vw, Vb, Aw, Ab, Bw, Bb,
                                              wsU, wsV, wsA, wsB);
  k_epass<0><<<dim3(NB), dim3(256), 0, stream>>>(e, ws0, wsA, wsB, wsV, Cb,
                                                 gamma_e, beta_e, ws6, wsP, out_e);
  k3a<<<dim3(64), dim3(256), 0, stream>>>(wsP, wsU, ws7, wsPB);
  k3b<<<dim3(1), dim3(256), 0, stream>>>(wsPB, ws6);
  k4_mlp<<<dim3(NB), dim3(256), 0, stream>>>(ws7, ws6, gamma_h, beta_h,
                                             W1, b1, W2, b2, h, out_h);
  k_epass<1><<<dim3(NB), dim3(256), 0, stream>>>(e, ws0, wsA, wsB, wsV, Cb,
                                                 gamma_e, beta_e, ws6, nullptr, out_e);
}